// Round 4
// baseline (4628.006 us; speedup 1.0000x reference)
//
#include <hip/hip_runtime.h>
#include <math.h>

#define NR 8192
#define D_IN 4
#define H_DIM 64
#define N_OSC 28
#define KC 28          // k-chunk (28 cos rows, then 28 sin rows)
#define BM 128
#define BN 256
#define TWO_PI_F 6.28318530717958647692f   // rounds to f32 2*pi

typedef float f32x4 __attribute__((ext_vector_type(4)));

__device__ __forceinline__ float modpos(float x) {
    float r = fmodf(x, TWO_PI_F);
    if (r < 0.0f) r += TWO_PI_F;   // np.mod semantics (divisor > 0)
    return r;
}

__device__ __forceinline__ unsigned int fmono(float f) {
    unsigned int u = __float_as_uint(f);
    return (u & 0x80000000u) ? ~u : (u | 0x80000000u);
}

// -------- phase encode + advance + trig + norm --------
__global__ __launch_bounds__(256) void encode_kernel(
    const float* __restrict__ detA, const float* __restrict__ detB,
    const float* __restrict__ W1, const float* __restrict__ b1,
    const float* __restrict__ W2, const float* __restrict__ b2,
    const float* __restrict__ freq,
    float* __restrict__ trigA, float* __restrict__ trigB,
    float* __restrict__ normA, float* __restrict__ normB)
{
    __shared__ float sW1[D_IN * H_DIM];
    __shared__ float sb1[H_DIM];
    __shared__ float sW2[H_DIM * N_OSC];
    __shared__ float sb2[N_OSC];
    __shared__ float sDelta[N_OSC];

    int t = threadIdx.x;
    for (int i = t; i < D_IN * H_DIM; i += 256) sW1[i] = W1[i];
    for (int i = t; i < H_DIM; i += 256) sb1[i] = b1[i];
    for (int i = t; i < H_DIM * N_OSC; i += 256) sW2[i] = W2[i];
    for (int i = t; i < N_OSC; i += 256) {
        sb2[i] = b2[i];
        float d = TWO_PI_F * freq[i];   // (TWO_PI * frequencies) in f32
        sDelta[i] = d * 0.01f;          // ... * DT
    }
    __syncthreads();

    int gid = blockIdx.x * 256 + t;
    bool isA = gid < NR;
    int row = isA ? gid : gid - NR;
    const float* det = isA ? detA : detB;
    float* trig = isA ? trigA : trigB;
    float* nrm  = isA ? normA : normB;

    float4 xv = *(const float4*)(det + (size_t)row * 4);
    float x0 = xv.x, x1 = xv.y, x2 = xv.z, x3 = xv.w;

    float h[H_DIM];
#pragma unroll
    for (int j = 0; j < H_DIM; ++j) {
        float a = x0 * sW1[0 * H_DIM + j];
        a += x1 * sW1[1 * H_DIM + j];
        a += x2 * sW1[2 * H_DIM + j];
        a += x3 * sW1[3 * H_DIM + j];
        a += sb1[j];
        h[j] = fmaxf(a, 0.0f);
    }

    float raw[N_OSC];
#pragma unroll
    for (int o = 0; o < N_OSC; ++o) raw[o] = 0.0f;
#pragma unroll
    for (int j = 0; j < H_DIM; ++j) {
        float hj = h[j];
#pragma unroll
        for (int o = 0; o < N_OSC; ++o) raw[o] += hj * sW2[j * N_OSC + o];
    }

    float csum = 0.0f;
#pragma unroll
    for (int o = 0; o < N_OSC; ++o) {
        float p = raw[o] + sb2[o];
        p = modpos(p);
        if (isA) {
            float d = sDelta[o];
#pragma unroll
            for (int s = 0; s < 5; ++s) { p = modpos(p + d); }
        }
        float sn, cs;
        sincosf(p, &sn, &cs);
        csum += cs * cs + sn * sn;
        trig[(size_t)o * NR + row] = cs;
        trig[(size_t)(N_OSC + o) * NR + row] = sn;
    }
    nrm[row] = sqrtf(csum) + 1e-6f;
}

// -------- sim tile GEMM (K=56 as 2x28), 8x16 per-thread tile, fused row-max --------
__global__ __launch_bounds__(256, 3) void sim_kernel(
    const float* __restrict__ trigA, const float* __restrict__ trigB,
    const float* __restrict__ normA, const float* __restrict__ normB,
    float* __restrict__ simOut, unsigned long long* __restrict__ rowMax)
{
    __shared__ __align__(16) float As[KC * BM];   // 14336 B
    __shared__ __align__(16) float Bs[KC * BN];   // 28672 B

    // bijective XCD swizzle: 2048 blocks, 8 XCDs, 256 contiguous tiles per XCD
    int bid = blockIdx.x;
    int swz = (bid & 7) * 256 + (bid >> 3);
    int bx = swz & 31;         // 32 col tiles (BN=256)
    int by = swz >> 5;         // 64 row tiles (BM=128)

    int r0 = by * BM;
    int c0 = bx * BN;
    int t = threadIdx.x;
    int tx = t & 15, ty = t >> 4;
    int tx4 = tx * 4, ty4 = ty * 4;

    float acc[8][16];
#pragma unroll
    for (int i = 0; i < 8; ++i)
#pragma unroll
        for (int j = 0; j < 16; ++j) acc[i][j] = 0.0f;

#pragma unroll
    for (int c = 0; c < 2; ++c) {
        // stage A: 28x128 (896 f4), B: 28x256 (1792 f4) => 2688 f4 over 256 thr
#pragma unroll
        for (int i = 0; i < 11; ++i) {
            int idx = t + i * 256;
            if (idx < 896) {
                int k = idx >> 5;
                int off = (idx & 31) << 2;
                *(float4*)&As[k * BM + off] =
                    *(const float4*)(trigA + (size_t)(c * KC + k) * NR + r0 + off);
            } else if (idx < 2688) {
                int f = idx - 896;
                int k = f >> 6;
                int off = (f & 63) << 2;
                *(float4*)&Bs[k * BN + off] =
                    *(const float4*)(trigB + (size_t)(c * KC + k) * NR + c0 + off);
            }
        }
        __syncthreads();

#pragma unroll
        for (int k = 0; k < KC; ++k) {
            float a[8], b[16];
            *(float4*)&a[0] = *(const float4*)&As[k * BM + ty4];
            *(float4*)&a[4] = *(const float4*)&As[k * BM + 64 + ty4];
            *(float4*)&b[0]  = *(const float4*)&Bs[k * BN + tx4];
            *(float4*)&b[4]  = *(const float4*)&Bs[k * BN + 64 + tx4];
            *(float4*)&b[8]  = *(const float4*)&Bs[k * BN + 128 + tx4];
            *(float4*)&b[12] = *(const float4*)&Bs[k * BN + 192 + tx4];
#pragma unroll
            for (int i = 0; i < 8; ++i)
#pragma unroll
                for (int j = 0; j < 16; ++j) acc[i][j] += a[i] * b[j];
        }
        __syncthreads();
    }

    float icn[16];
    int gc[16];
#pragma unroll
    for (int j = 0; j < 16; ++j) {
        int lc = (j >> 2) * 64 + tx4 + (j & 3);
        gc[j] = c0 + lc;
        icn[j] = 1.0f / normB[c0 + lc];
    }

#pragma unroll
    for (int i = 0; i < 8; ++i) {
        int lr = (i < 4) ? (ty4 + i) : (64 + ty4 + (i - 4));
        int grow = r0 + lr;
        float irn = 1.0f / normA[grow];
        float sv[16];
#pragma unroll
        for (int j = 0; j < 16; ++j) sv[j] = acc[i][j] * (irn * icn[j]);

        size_t base = (size_t)grow * NR + c0;
#pragma unroll
        for (int g = 0; g < 4; ++g) {
            f32x4 w;
            w.x = sv[g * 4 + 0]; w.y = sv[g * 4 + 1];
            w.z = sv[g * 4 + 2]; w.w = sv[g * 4 + 3];
            __builtin_nontemporal_store(w, (f32x4*)&simOut[base + g * 64 + tx4]);
        }

        // packed (monotone-sim | ~col) row max; smaller col wins ties
        unsigned long long key = 0ull;
#pragma unroll
        for (int j = 0; j < 16; ++j) {
            unsigned long long kk = ((unsigned long long)fmono(sv[j]) << 32)
                                  | (unsigned long long)(0xFFFFFFFFu - (unsigned)gc[j]);
            if (kk > key) key = kk;
        }
        // reduce across the 16 tx lanes (lane bits 0..3)
#pragma unroll
        for (int d = 1; d < 16; d <<= 1) {
            unsigned int lo = (unsigned int)key;
            unsigned int hi = (unsigned int)(key >> 32);
            unsigned int olo = __shfl_xor(lo, d, 64);
            unsigned int ohi = __shfl_xor(hi, d, 64);
            unsigned long long o = ((unsigned long long)ohi << 32) | olo;
            if (o > key) key = o;
        }
        if (tx == 0) atomicMax(&rowMax[grow], key);
    }
}

// -------- per-row: init matches, claim column --------
__global__ __launch_bounds__(256) void rowwin_kernel(
    const unsigned long long* __restrict__ rowMax,
    unsigned long long* __restrict__ colWin,
    float* __restrict__ outMatches)
{
    int r = blockIdx.x * 256 + threadIdx.x;
    if (r >= NR) return;
    outMatches[r] = -1.0f;
    unsigned long long key = rowMax[r];
    unsigned int m = (unsigned int)(key >> 32);
    unsigned int bits = (m & 0x80000000u) ? (m ^ 0x80000000u) : ~m;
    float ms = __uint_as_float(bits);
    unsigned int col = 0xFFFFFFFFu - (unsigned int)key;
    if (ms > 0.3f) {
        unsigned long long ck = ((unsigned long long)m << 32)
                              | (unsigned long long)(0xFFFFFFFFu - (unsigned)r);
        atomicMax(&colWin[col], ck);
    }
}

// -------- per-column: winner takes the column --------
__global__ __launch_bounds__(256) void colfin_kernel(
    const unsigned long long* __restrict__ colWin,
    float* __restrict__ outMatches)
{
    int j = blockIdx.x * 256 + threadIdx.x;
    if (j >= NR) return;
    unsigned long long w = colWin[j];
    if (w != 0ull) {
        unsigned int r = 0xFFFFFFFFu - (unsigned int)w;
        outMatches[r] = (float)j;
    }
}

extern "C" void kernel_launch(void* const* d_in, const int* in_sizes, int n_in,
                              void* d_out, int out_size, void* d_ws, size_t ws_size,
                              hipStream_t stream) {
    const float* detA = (const float*)d_in[0];
    const float* detB = (const float*)d_in[1];
    const float* W1   = (const float*)d_in[2];
    const float* b1   = (const float*)d_in[3];
    const float* W2   = (const float*)d_in[4];
    const float* b2   = (const float*)d_in[5];
    const float* freq = (const float*)d_in[6];
    float* out = (float*)d_out;

    char* ws = (char*)d_ws;
    float* trigA = (float*)(ws);                         // 56*8192*4 = 1,835,008
    float* trigB = (float*)(ws + 1835008);               // 1,835,008
    float* normA = (float*)(ws + 3670016);               // 32,768
    float* normB = (float*)(ws + 3702784);               // 32,768
    unsigned long long* rowMax = (unsigned long long*)(ws + 3735552); // 65,536
    unsigned long long* colWin = (unsigned long long*)(ws + 3801088); // 65,536

    (void)hipMemsetAsync(rowMax, 0, NR * 8, stream);
    (void)hipMemsetAsync(colWin, 0, NR * 8, stream);

    encode_kernel<<<64, 256, 0, stream>>>(detA, detB, W1, b1, W2, b2, freq,
                                          trigA, trigB, normA, normB);
    sim_kernel<<<(NR / BM) * (NR / BN), 256, 0, stream>>>(
        trigA, trigB, normA, normB, out + NR, rowMax);
    rowwin_kernel<<<NR / 256, 256, 0, stream>>>(rowMax, colWin, out);
    colfin_kernel<<<NR / 256, 256, 0, stream>>>(colWin, out);
}

// Round 5
// 4513.050 us; speedup vs baseline: 1.0255x; 1.0255x over previous
//
#include <hip/hip_runtime.h>
#include <math.h>

#define NR 8192
#define D_IN 4
#define H_DIM 64
#define N_OSC 28
#define KC 28          // k-chunk (28 cos rows, then 28 sin rows)
#define BM 128
#define BN 256
#define TWO_PI_F 6.28318530717958647692f   // rounds to f32 2*pi

typedef float f32x4 __attribute__((ext_vector_type(4)));

__device__ __forceinline__ float modpos(float x) {
    float r = fmodf(x, TWO_PI_F);
    if (r < 0.0f) r += TWO_PI_F;   // np.mod semantics (divisor > 0)
    return r;
}

__device__ __forceinline__ unsigned int fmono(float f) {
    unsigned int u = __float_as_uint(f);
    return (u & 0x80000000u) ? ~u : (u | 0x80000000u);
}

// -------- phase encode + advance + trig + norm --------
__global__ __launch_bounds__(256) void encode_kernel(
    const float* __restrict__ detA, const float* __restrict__ detB,
    const float* __restrict__ W1, const float* __restrict__ b1,
    const float* __restrict__ W2, const float* __restrict__ b2,
    const float* __restrict__ freq,
    float* __restrict__ trigA, float* __restrict__ trigB,
    float* __restrict__ normA, float* __restrict__ normB)
{
    __shared__ float sW1[D_IN * H_DIM];
    __shared__ float sb1[H_DIM];
    __shared__ float sW2[H_DIM * N_OSC];
    __shared__ float sb2[N_OSC];
    __shared__ float sDelta[N_OSC];

    int t = threadIdx.x;
    for (int i = t; i < D_IN * H_DIM; i += 256) sW1[i] = W1[i];
    for (int i = t; i < H_DIM; i += 256) sb1[i] = b1[i];
    for (int i = t; i < H_DIM * N_OSC; i += 256) sW2[i] = W2[i];
    for (int i = t; i < N_OSC; i += 256) {
        sb2[i] = b2[i];
        float d = TWO_PI_F * freq[i];   // (TWO_PI * frequencies) in f32
        sDelta[i] = d * 0.01f;          // ... * DT
    }
    __syncthreads();

    int gid = blockIdx.x * 256 + t;
    bool isA = gid < NR;
    int row = isA ? gid : gid - NR;
    const float* det = isA ? detA : detB;
    float* trig = isA ? trigA : trigB;
    float* nrm  = isA ? normA : normB;

    float4 xv = *(const float4*)(det + (size_t)row * 4);
    float x0 = xv.x, x1 = xv.y, x2 = xv.z, x3 = xv.w;

    float h[H_DIM];
#pragma unroll
    for (int j = 0; j < H_DIM; ++j) {
        float a = x0 * sW1[0 * H_DIM + j];
        a += x1 * sW1[1 * H_DIM + j];
        a += x2 * sW1[2 * H_DIM + j];
        a += x3 * sW1[3 * H_DIM + j];
        a += sb1[j];
        h[j] = fmaxf(a, 0.0f);
    }

    float raw[N_OSC];
#pragma unroll
    for (int o = 0; o < N_OSC; ++o) raw[o] = 0.0f;
#pragma unroll
    for (int j = 0; j < H_DIM; ++j) {
        float hj = h[j];
#pragma unroll
        for (int o = 0; o < N_OSC; ++o) raw[o] += hj * sW2[j * N_OSC + o];
    }

    float csum = 0.0f;
#pragma unroll
    for (int o = 0; o < N_OSC; ++o) {
        float p = raw[o] + sb2[o];
        p = modpos(p);
        if (isA) {
            float d = sDelta[o];
#pragma unroll
            for (int s = 0; s < 5; ++s) { p = modpos(p + d); }
        }
        float sn, cs;
        sincosf(p, &sn, &cs);
        csum += cs * cs + sn * sn;
        trig[(size_t)o * NR + row] = cs;
        trig[(size_t)(N_OSC + o) * NR + row] = sn;
    }
    nrm[row] = sqrtf(csum) + 1e-6f;
}

// -------- sim tile GEMM (K=56 as 2x28), 8x16 per-thread tile, fused row-max --------
__global__ __launch_bounds__(256, 2) void sim_kernel(
    const float* __restrict__ trigA, const float* __restrict__ trigB,
    const float* __restrict__ normA, const float* __restrict__ normB,
    float* __restrict__ simOut, unsigned long long* __restrict__ rowMax)
{
    __shared__ __align__(16) float As[KC * BM];   // 14336 B
    __shared__ __align__(16) float Bs[KC * BN];   // 28672 B

    // bijective XCD swizzle: 2048 blocks, 8 XCDs, 256 contiguous tiles per XCD
    int bid = blockIdx.x;
    int swz = (bid & 7) * 256 + (bid >> 3);
    int bx = swz & 31;         // 32 col tiles (BN=256)
    int by = swz >> 5;         // 64 row tiles (BM=128)

    int r0 = by * BM;
    int c0 = bx * BN;
    int t = threadIdx.x;
    int tx = t & 15, ty = t >> 4;
    int tx4 = tx * 4, ty4 = ty * 4;

    float acc[8][16];
#pragma unroll
    for (int i = 0; i < 8; ++i)
#pragma unroll
        for (int j = 0; j < 16; ++j) acc[i][j] = 0.0f;

#pragma unroll
    for (int c = 0; c < 2; ++c) {
        // stage A: 28x128 (896 f4), B: 28x256 (1792 f4) => 2688 f4 over 256 thr
#pragma unroll
        for (int i = 0; i < 11; ++i) {
            int idx = t + i * 256;
            if (idx < 896) {
                int k = idx >> 5;
                int off = (idx & 31) << 2;
                *(float4*)&As[k * BM + off] =
                    *(const float4*)(trigA + (size_t)(c * KC + k) * NR + r0 + off);
            } else if (idx < 2688) {
                int f = idx - 896;
                int k = f >> 6;
                int off = (f & 63) << 2;
                *(float4*)&Bs[k * BN + off] =
                    *(const float4*)(trigB + (size_t)(c * KC + k) * NR + c0 + off);
            }
        }
        __syncthreads();

#pragma unroll
        for (int k = 0; k < KC; ++k) {
            float a[8], b[16];
            *(float4*)&a[0] = *(const float4*)&As[k * BM + ty4];
            *(float4*)&a[4] = *(const float4*)&As[k * BM + 64 + ty4];
            *(float4*)&b[0]  = *(const float4*)&Bs[k * BN + tx4];
            *(float4*)&b[4]  = *(const float4*)&Bs[k * BN + 64 + tx4];
            *(float4*)&b[8]  = *(const float4*)&Bs[k * BN + 128 + tx4];
            *(float4*)&b[12] = *(const float4*)&Bs[k * BN + 192 + tx4];
#pragma unroll
            for (int i = 0; i < 8; ++i)
#pragma unroll
                for (int j = 0; j < 16; ++j) acc[i][j] += a[i] * b[j];
        }
        __syncthreads();
    }

    float icn[16];
    int gc[16];
#pragma unroll
    for (int j = 0; j < 16; ++j) {
        int lc = (j >> 2) * 64 + tx4 + (j & 3);
        gc[j] = c0 + lc;
        icn[j] = 1.0f / normB[c0 + lc];
    }

#pragma unroll
    for (int i = 0; i < 8; ++i) {
        int lr = (i < 4) ? (ty4 + i) : (64 + ty4 + (i - 4));
        int grow = r0 + lr;
        float irn = 1.0f / normA[grow];
        float sv[16];
#pragma unroll
        for (int j = 0; j < 16; ++j) sv[j] = acc[i][j] * (irn * icn[j]);

        size_t base = (size_t)grow * NR + c0;
#pragma unroll
        for (int g = 0; g < 4; ++g) {
            f32x4 w;
            w.x = sv[g * 4 + 0]; w.y = sv[g * 4 + 1];
            w.z = sv[g * 4 + 2]; w.w = sv[g * 4 + 3];
            __builtin_nontemporal_store(w, (f32x4*)&simOut[base + g * 64 + tx4]);
        }

        // packed (monotone-sim | ~col) row max; smaller col wins ties
        unsigned long long key = 0ull;
#pragma unroll
        for (int j = 0; j < 16; ++j) {
            unsigned long long kk = ((unsigned long long)fmono(sv[j]) << 32)
                                  | (unsigned long long)(0xFFFFFFFFu - (unsigned)gc[j]);
            if (kk > key) key = kk;
        }
        // reduce across the 16 tx lanes (lane bits 0..3)
#pragma unroll
        for (int d = 1; d < 16; d <<= 1) {
            unsigned int lo = (unsigned int)key;
            unsigned int hi = (unsigned int)(key >> 32);
            unsigned int olo = __shfl_xor(lo, d, 64);
            unsigned int ohi = __shfl_xor(hi, d, 64);
            unsigned long long o = ((unsigned long long)ohi << 32) | olo;
            if (o > key) key = o;
        }
        if (tx == 0) atomicMax(&rowMax[grow], key);
    }
}

// -------- per-row: init matches, claim column --------
__global__ __launch_bounds__(256) void rowwin_kernel(
    const unsigned long long* __restrict__ rowMax,
    unsigned long long* __restrict__ colWin,
    float* __restrict__ outMatches)
{
    int r = blockIdx.x * 256 + threadIdx.x;
    if (r >= NR) return;
    outMatches[r] = -1.0f;
    unsigned long long key = rowMax[r];
    unsigned int m = (unsigned int)(key >> 32);
    unsigned int bits = (m & 0x80000000u) ? (m ^ 0x80000000u) : ~m;
    float ms = __uint_as_float(bits);
    unsigned int col = 0xFFFFFFFFu - (unsigned int)key;
    if (ms > 0.3f) {
        unsigned long long ck = ((unsigned long long)m << 32)
                              | (unsigned long long)(0xFFFFFFFFu - (unsigned)r);
        atomicMax(&colWin[col], ck);
    }
}

// -------- per-column: winner takes the column --------
__global__ __launch_bounds__(256) void colfin_kernel(
    const unsigned long long* __restrict__ colWin,
    float* __restrict__ outMatches)
{
    int j = blockIdx.x * 256 + threadIdx.x;
    if (j >= NR) return;
    unsigned long long w = colWin[j];
    if (w != 0ull) {
        unsigned int r = 0xFFFFFFFFu - (unsigned int)w;
        outMatches[r] = (float)j;
    }
}

extern "C" void kernel_launch(void* const* d_in, const int* in_sizes, int n_in,
                              void* d_out, int out_size, void* d_ws, size_t ws_size,
                              hipStream_t stream) {
    const float* detA = (const float*)d_in[0];
    const float* detB = (const float*)d_in[1];
    const float* W1   = (const float*)d_in[2];
    const float* b1   = (const float*)d_in[3];
    const float* W2   = (const float*)d_in[4];
    const float* b2   = (const float*)d_in[5];
    const float* freq = (const float*)d_in[6];
    float* out = (float*)d_out;

    char* ws = (char*)d_ws;
    float* trigA = (float*)(ws);                         // 56*8192*4 = 1,835,008
    float* trigB = (float*)(ws + 1835008);               // 1,835,008
    float* normA = (float*)(ws + 3670016);               // 32,768
    float* normB = (float*)(ws + 3702784);               // 32,768
    unsigned long long* rowMax = (unsigned long long*)(ws + 3735552); // 65,536
    unsigned long long* colWin = (unsigned long long*)(ws + 3801088); // 65,536

    (void)hipMemsetAsync(rowMax, 0, NR * 8, stream);
    (void)hipMemsetAsync(colWin, 0, NR * 8, stream);

    encode_kernel<<<64, 256, 0, stream>>>(detA, detB, W1, b1, W2, b2, freq,
                                          trigA, trigB, normA, normB);
    sim_kernel<<<(NR / BM) * (NR / BN), 256, 0, stream>>>(
        trigA, trigB, normA, normB, out + NR, rowMax);
    rowwin_kernel<<<NR / 256, 256, 0, stream>>>(rowMax, colWin, out);
    colfin_kernel<<<NR / 256, 256, 0, stream>>>(colWin, out);
}

// Round 6
// 3250.791 us; speedup vs baseline: 1.4237x; 1.3883x over previous
//
#include <hip/hip_runtime.h>
#include <math.h>

#define NR 8192
#define D_IN 4
#define H_DIM 64
#define N_OSC 28
#define KC 28          // k-chunk (28 cos rows, then 28 sin rows)
#define BM 128
#define BN 256
#define TWO_PI_F 6.28318530717958647692f   // rounds to f32 2*pi

typedef float f32x4 __attribute__((ext_vector_type(4)));

__device__ __forceinline__ float modpos(float x) {
    float r = fmodf(x, TWO_PI_F);
    if (r < 0.0f) r += TWO_PI_F;   // np.mod semantics (divisor > 0)
    return r;
}

__device__ __forceinline__ unsigned int fmono(float f) {
    unsigned int u = __float_as_uint(f);
    return (u & 0x80000000u) ? ~u : (u | 0x80000000u);
}

// -------- phase encode + advance + trig + norm --------
__global__ __launch_bounds__(256) void encode_kernel(
    const float* __restrict__ detA, const float* __restrict__ detB,
    const float* __restrict__ W1, const float* __restrict__ b1,
    const float* __restrict__ W2, const float* __restrict__ b2,
    const float* __restrict__ freq,
    float* __restrict__ trigA, float* __restrict__ trigB,
    float* __restrict__ normA, float* __restrict__ normB)
{
    __shared__ float sW1[D_IN * H_DIM];
    __shared__ float sb1[H_DIM];
    __shared__ float sW2[H_DIM * N_OSC];
    __shared__ float sb2[N_OSC];
    __shared__ float sDelta[N_OSC];

    int t = threadIdx.x;
    for (int i = t; i < D_IN * H_DIM; i += 256) sW1[i] = W1[i];
    for (int i = t; i < H_DIM; i += 256) sb1[i] = b1[i];
    for (int i = t; i < H_DIM * N_OSC; i += 256) sW2[i] = W2[i];
    for (int i = t; i < N_OSC; i += 256) {
        sb2[i] = b2[i];
        float d = TWO_PI_F * freq[i];   // (TWO_PI * frequencies) in f32
        sDelta[i] = d * 0.01f;          // ... * DT
    }
    __syncthreads();

    int gid = blockIdx.x * 256 + t;
    bool isA = gid < NR;
    int row = isA ? gid : gid - NR;
    const float* det = isA ? detA : detB;
    float* trig = isA ? trigA : trigB;
    float* nrm  = isA ? normA : normB;

    float4 xv = *(const float4*)(det + (size_t)row * 4);
    float x0 = xv.x, x1 = xv.y, x2 = xv.z, x3 = xv.w;

    float h[H_DIM];
#pragma unroll
    for (int j = 0; j < H_DIM; ++j) {
        float a = x0 * sW1[0 * H_DIM + j];
        a += x1 * sW1[1 * H_DIM + j];
        a += x2 * sW1[2 * H_DIM + j];
        a += x3 * sW1[3 * H_DIM + j];
        a += sb1[j];
        h[j] = fmaxf(a, 0.0f);
    }

    float raw[N_OSC];
#pragma unroll
    for (int o = 0; o < N_OSC; ++o) raw[o] = 0.0f;
#pragma unroll
    for (int j = 0; j < H_DIM; ++j) {
        float hj = h[j];
#pragma unroll
        for (int o = 0; o < N_OSC; ++o) raw[o] += hj * sW2[j * N_OSC + o];
    }

    float csum = 0.0f;
#pragma unroll
    for (int o = 0; o < N_OSC; ++o) {
        float p = raw[o] + sb2[o];
        p = modpos(p);
        if (isA) {
            float d = sDelta[o];
#pragma unroll
            for (int s = 0; s < 5; ++s) { p = modpos(p + d); }
        }
        float sn, cs;
        sincosf(p, &sn, &cs);
        csum += cs * cs + sn * sn;
        trig[(size_t)o * NR + row] = cs;
        trig[(size_t)(N_OSC + o) * NR + row] = sn;
    }
    nrm[row] = sqrtf(csum) + 1e-6f;
}

// -------- sim tile GEMM (K=56 as 2x28), 8x16 per-thread tile, fused row-max --------
__global__ __launch_bounds__(256, 1) void sim_kernel(
    const float* __restrict__ trigA, const float* __restrict__ trigB,
    const float* __restrict__ normA, const float* __restrict__ normB,
    float* __restrict__ simOut, unsigned long long* __restrict__ rowMax)
{
    __shared__ __align__(16) float As[KC * BM];   // 14336 B
    __shared__ __align__(16) float Bs[KC * BN];   // 28672 B

    // bijective XCD swizzle: 2048 blocks, 8 XCDs, 256 contiguous tiles per XCD
    int bid = blockIdx.x;
    int swz = (bid & 7) * 256 + (bid >> 3);
    int bx = swz & 31;         // 32 col tiles (BN=256)
    int by = swz >> 5;         // 64 row tiles (BM=128)

    int r0 = by * BM;
    int c0 = bx * BN;
    int t = threadIdx.x;
    int tx = t & 15, ty = t >> 4;
    int tx4 = tx * 4, ty4 = ty * 4;

    float acc[8][16];
#pragma unroll
    for (int i = 0; i < 8; ++i)
#pragma unroll
        for (int j = 0; j < 16; ++j) acc[i][j] = 0.0f;

#pragma unroll
    for (int c = 0; c < 2; ++c) {
        // stage A: 28x128 (896 f4), B: 28x256 (1792 f4) => 2688 f4 over 256 thr
#pragma unroll
        for (int i = 0; i < 11; ++i) {
            int idx = t + i * 256;
            if (idx < 896) {
                int k = idx >> 5;
                int off = (idx & 31) << 2;
                *(float4*)&As[k * BM + off] =
                    *(const float4*)(trigA + (size_t)(c * KC + k) * NR + r0 + off);
            } else if (idx < 2688) {
                int f = idx - 896;
                int k = f >> 6;
                int off = (f & 63) << 2;
                *(float4*)&Bs[k * BN + off] =
                    *(const float4*)(trigB + (size_t)(c * KC + k) * NR + c0 + off);
            }
        }
        __syncthreads();

#pragma unroll
        for (int k = 0; k < KC; ++k) {
            float a[8], b[16];
            *(float4*)&a[0] = *(const float4*)&As[k * BM + ty4];
            *(float4*)&a[4] = *(const float4*)&As[k * BM + 64 + ty4];
            *(float4*)&b[0]  = *(const float4*)&Bs[k * BN + tx4];
            *(float4*)&b[4]  = *(const float4*)&Bs[k * BN + 64 + tx4];
            *(float4*)&b[8]  = *(const float4*)&Bs[k * BN + 128 + tx4];
            *(float4*)&b[12] = *(const float4*)&Bs[k * BN + 192 + tx4];
#pragma unroll
            for (int i = 0; i < 8; ++i)
#pragma unroll
                for (int j = 0; j < 16; ++j) acc[i][j] += a[i] * b[j];
        }
        __syncthreads();
    }

    float icn[16];
    int gc[16];
#pragma unroll
    for (int j = 0; j < 16; ++j) {
        int lc = (j >> 2) * 64 + tx4 + (j & 3);
        gc[j] = c0 + lc;
        icn[j] = 1.0f / normB[c0 + lc];
    }

#pragma unroll
    for (int i = 0; i < 8; ++i) {
        int lr = (i < 4) ? (ty4 + i) : (64 + ty4 + (i - 4));
        int grow = r0 + lr;
        float irn = 1.0f / normA[grow];
        float sv[16];
#pragma unroll
        for (int j = 0; j < 16; ++j) sv[j] = acc[i][j] * (irn * icn[j]);

        size_t base = (size_t)grow * NR + c0;
#pragma unroll
        for (int g = 0; g < 4; ++g) {
            f32x4 w;
            w.x = sv[g * 4 + 0]; w.y = sv[g * 4 + 1];
            w.z = sv[g * 4 + 2]; w.w = sv[g * 4 + 3];
            __builtin_nontemporal_store(w, (f32x4*)&simOut[base + g * 64 + tx4]);
        }

        // packed (monotone-sim | ~col) row max; smaller col wins ties
        unsigned long long key = 0ull;
#pragma unroll
        for (int j = 0; j < 16; ++j) {
            unsigned long long kk = ((unsigned long long)fmono(sv[j]) << 32)
                                  | (unsigned long long)(0xFFFFFFFFu - (unsigned)gc[j]);
            if (kk > key) key = kk;
        }
        // reduce across the 16 tx lanes (lane bits 0..3)
#pragma unroll
        for (int d = 1; d < 16; d <<= 1) {
            unsigned int lo = (unsigned int)key;
            unsigned int hi = (unsigned int)(key >> 32);
            unsigned int olo = __shfl_xor(lo, d, 64);
            unsigned int ohi = __shfl_xor(hi, d, 64);
            unsigned long long o = ((unsigned long long)ohi << 32) | olo;
            if (o > key) key = o;
        }
        if (tx == 0) atomicMax(&rowMax[grow], key);
    }
}

// -------- per-row: init matches, claim column --------
__global__ __launch_bounds__(256) void rowwin_kernel(
    const unsigned long long* __restrict__ rowMax,
    unsigned long long* __restrict__ colWin,
    float* __restrict__ outMatches)
{
    int r = blockIdx.x * 256 + threadIdx.x;
    if (r >= NR) return;
    outMatches[r] = -1.0f;
    unsigned long long key = rowMax[r];
    unsigned int m = (unsigned int)(key >> 32);
    unsigned int bits = (m & 0x80000000u) ? (m ^ 0x80000000u) : ~m;
    float ms = __uint_as_float(bits);
    unsigned int col = 0xFFFFFFFFu - (unsigned int)key;
    if (ms > 0.3f) {
        unsigned long long ck = ((unsigned long long)m << 32)
                              | (unsigned long long)(0xFFFFFFFFu - (unsigned)r);
        atomicMax(&colWin[col], ck);
    }
}

// -------- per-column: winner takes the column --------
__global__ __launch_bounds__(256) void colfin_kernel(
    const unsigned long long* __restrict__ colWin,
    float* __restrict__ outMatches)
{
    int j = blockIdx.x * 256 + threadIdx.x;
    if (j >= NR) return;
    unsigned long long w = colWin[j];
    if (w != 0ull) {
        unsigned int r = 0xFFFFFFFFu - (unsigned int)w;
        outMatches[r] = (float)j;
    }
}

extern "C" void kernel_launch(void* const* d_in, const int* in_sizes, int n_in,
                              void* d_out, int out_size, void* d_ws, size_t ws_size,
                              hipStream_t stream) {
    const float* detA = (const float*)d_in[0];
    const float* detB = (const float*)d_in[1];
    const float* W1   = (const float*)d_in[2];
    const float* b1   = (const float*)d_in[3];
    const float* W2   = (const float*)d_in[4];
    const float* b2   = (const float*)d_in[5];
    const float* freq = (const float*)d_in[6];
    float* out = (float*)d_out;

    char* ws = (char*)d_ws;
    float* trigA = (float*)(ws);                         // 56*8192*4 = 1,835,008
    float* trigB = (float*)(ws + 1835008);               // 1,835,008
    float* normA = (float*)(ws + 3670016);               // 32,768
    float* normB = (float*)(ws + 3702784);               // 32,768
    unsigned long long* rowMax = (unsigned long long*)(ws + 3735552); // 65,536
    unsigned long long* colWin = (unsigned long long*)(ws + 3801088); // 65,536

    (void)hipMemsetAsync(rowMax, 0, NR * 8, stream);
    (void)hipMemsetAsync(colWin, 0, NR * 8, stream);

    encode_kernel<<<64, 256, 0, stream>>>(detA, detB, W1, b1, W2, b2, freq,
                                          trigA, trigB, normA, normB);
    sim_kernel<<<(NR / BM) * (NR / BN), 256, 0, stream>>>(
        trigA, trigB, normA, normB, out + NR, rowMax);
    rowwin_kernel<<<NR / 256, 256, 0, stream>>>(rowMax, colWin, out);
    colfin_kernel<<<NR / 256, 256, 0, stream>>>(colWin, out);
}

// Round 7
// 176.107 us; speedup vs baseline: 26.2795x; 18.4591x over previous
//
#include <hip/hip_runtime.h>
#include <math.h>

#define NR 8192
#define D_IN 4
#define H_DIM 64
#define N_OSC 28
#define KC 28          // k-chunk (28 cos rows, then 28 sin rows)
#define BM 128
#define BN 256
#define TWO_PI_F 6.28318530717958647692f   // rounds to f32 2*pi

typedef float f32x4 __attribute__((ext_vector_type(4)));

#define AS3(p) ((__attribute__((address_space(3))) void*)(p))
#define AS1C(p) ((const __attribute__((address_space(1))) void*)(p))

__device__ __forceinline__ float modpos(float x) {
    float r = fmodf(x, TWO_PI_F);
    if (r < 0.0f) r += TWO_PI_F;   // np.mod semantics (divisor > 0)
    return r;
}

__device__ __forceinline__ unsigned int fmono(float f) {
    unsigned int u = __float_as_uint(f);
    return (u & 0x80000000u) ? ~u : (u | 0x80000000u);
}

// -------- phase encode + advance + trig + norm --------
__global__ __launch_bounds__(256) void encode_kernel(
    const float* __restrict__ detA, const float* __restrict__ detB,
    const float* __restrict__ W1, const float* __restrict__ b1,
    const float* __restrict__ W2, const float* __restrict__ b2,
    const float* __restrict__ freq,
    float* __restrict__ trigA, float* __restrict__ trigB,
    float* __restrict__ normA, float* __restrict__ normB)
{
    __shared__ float sW1[D_IN * H_DIM];
    __shared__ float sb1[H_DIM];
    __shared__ float sW2[H_DIM * N_OSC];
    __shared__ float sb2[N_OSC];
    __shared__ float sDelta[N_OSC];

    int t = threadIdx.x;
    for (int i = t; i < D_IN * H_DIM; i += 256) sW1[i] = W1[i];
    for (int i = t; i < H_DIM; i += 256) sb1[i] = b1[i];
    for (int i = t; i < H_DIM * N_OSC; i += 256) sW2[i] = W2[i];
    for (int i = t; i < N_OSC; i += 256) {
        sb2[i] = b2[i];
        float d = TWO_PI_F * freq[i];   // (TWO_PI * frequencies) in f32
        sDelta[i] = d * 0.01f;          // ... * DT
    }
    __syncthreads();

    int gid = blockIdx.x * 256 + t;
    bool isA = gid < NR;
    int row = isA ? gid : gid - NR;
    const float* det = isA ? detA : detB;
    float* trig = isA ? trigA : trigB;
    float* nrm  = isA ? normA : normB;

    float4 xv = *(const float4*)(det + (size_t)row * 4);
    float x0 = xv.x, x1 = xv.y, x2 = xv.z, x3 = xv.w;

    float h[H_DIM];
#pragma unroll
    for (int j = 0; j < H_DIM; ++j) {
        float a = x0 * sW1[0 * H_DIM + j];
        a += x1 * sW1[1 * H_DIM + j];
        a += x2 * sW1[2 * H_DIM + j];
        a += x3 * sW1[3 * H_DIM + j];
        a += sb1[j];
        h[j] = fmaxf(a, 0.0f);
    }

    float raw[N_OSC];
#pragma unroll
    for (int o = 0; o < N_OSC; ++o) raw[o] = 0.0f;
#pragma unroll
    for (int j = 0; j < H_DIM; ++j) {
        float hj = h[j];
#pragma unroll
        for (int o = 0; o < N_OSC; ++o) raw[o] += hj * sW2[j * N_OSC + o];
    }

    float csum = 0.0f;
#pragma unroll
    for (int o = 0; o < N_OSC; ++o) {
        float p = raw[o] + sb2[o];
        p = modpos(p);
        if (isA) {
            float d = sDelta[o];
#pragma unroll
            for (int s = 0; s < 5; ++s) { p = modpos(p + d); }
        }
        float sn, cs;
        sincosf(p, &sn, &cs);
        csum += cs * cs + sn * sn;
        trig[(size_t)o * NR + row] = cs;
        trig[(size_t)(N_OSC + o) * NR + row] = sn;
    }
    nrm[row] = sqrtf(csum) + 1e-6f;
}

// -------- sim tile GEMM (K=56 as 2x28), 8x16 tile, global_load_lds staging --------
__global__ __launch_bounds__(256, 1) void sim_kernel(
    const float* __restrict__ trigA, const float* __restrict__ trigB,
    const float* __restrict__ normA, const float* __restrict__ normB,
    float* __restrict__ simOut, unsigned long long* __restrict__ rowMax)
{
    __shared__ __align__(16) float As[KC * BM];   // 14336 B
    __shared__ __align__(16) float Bs[KC * BN];   // 28672 B

    // bijective XCD swizzle: 2048 blocks, 8 XCDs, 256 contiguous tiles per XCD
    int bid = blockIdx.x;
    int swz = (bid & 7) * 256 + (bid >> 3);
    int bx = swz & 31;         // 32 col tiles (BN=256)
    int by = swz >> 5;         // 64 row tiles (BM=128)

    int r0 = by * BM;
    int c0 = bx * BN;
    int t = threadIdx.x;
    int tx = t & 15, ty = t >> 4;
    int tx4 = tx * 4, ty4 = ty * 4;
    int w = t >> 6, l = t & 63;

    float acc[8][16];
#pragma unroll
    for (int i = 0; i < 8; ++i)
#pragma unroll
        for (int j = 0; j < 16; ++j) acc[i][j] = 0.0f;

#pragma unroll
    for (int c = 0; c < 2; ++c) {
        // Zero-VGPR staging: each global_load_lds moves 64 lanes x 16B = 1024 B.
        // A-chunk: 28 rows x 512 B -> 14 units of 2 rows; lane's global row =
        // 2u + (l>>5), col = (l&31)*4, matching LDS dest base + l*16.
        for (int u = w; u < 14; u += 4) {
            const float* g = trigA + (size_t)(c * KC + 2 * u + (l >> 5)) * NR
                           + r0 + (l & 31) * 4;
            __builtin_amdgcn_global_load_lds(AS1C(g), AS3(&As[u * 256]), 16, 0, 0);
        }
        // B-chunk: 28 rows x 1024 B -> 1 unit per row
        for (int v = w; v < KC; v += 4) {
            const float* g = trigB + (size_t)(c * KC + v) * NR + c0 + l * 4;
            __builtin_amdgcn_global_load_lds(AS1C(g), AS3(&Bs[v * 256]), 16, 0, 0);
        }
        __builtin_amdgcn_sched_barrier(0);
        __syncthreads();

#pragma unroll 4
        for (int k = 0; k < KC; ++k) {
            float a[8], b[16];
            *(float4*)&a[0] = *(const float4*)&As[k * BM + ty4];
            *(float4*)&a[4] = *(const float4*)&As[k * BM + 64 + ty4];
            *(float4*)&b[0]  = *(const float4*)&Bs[k * BN + tx4];
            *(float4*)&b[4]  = *(const float4*)&Bs[k * BN + 64 + tx4];
            *(float4*)&b[8]  = *(const float4*)&Bs[k * BN + 128 + tx4];
            *(float4*)&b[12] = *(const float4*)&Bs[k * BN + 192 + tx4];
#pragma unroll
            for (int i = 0; i < 8; ++i)
#pragma unroll
                for (int j = 0; j < 16; ++j) acc[i][j] += a[i] * b[j];
        }
        __syncthreads();
    }

    float icn[16];
    int gc[16];
#pragma unroll
    for (int j = 0; j < 16; ++j) {
        int lc = (j >> 2) * 64 + tx4 + (j & 3);
        gc[j] = c0 + lc;
        icn[j] = 1.0f / normB[c0 + lc];
    }

#pragma unroll
    for (int i = 0; i < 8; ++i) {
        int lr = (i < 4) ? (ty4 + i) : (64 + ty4 + (i - 4));
        int grow = r0 + lr;
        float irn = 1.0f / normA[grow];
        float sv[16];
#pragma unroll
        for (int j = 0; j < 16; ++j) sv[j] = acc[i][j] * (irn * icn[j]);

        size_t base = (size_t)grow * NR + c0;
#pragma unroll
        for (int g = 0; g < 4; ++g) {
            f32x4 wv;
            wv.x = sv[g * 4 + 0]; wv.y = sv[g * 4 + 1];
            wv.z = sv[g * 4 + 2]; wv.w = sv[g * 4 + 3];
            __builtin_nontemporal_store(wv, (f32x4*)&simOut[base + g * 64 + tx4]);
        }

        // packed (monotone-sim | ~col) row max; smaller col wins ties
        unsigned long long key = 0ull;
#pragma unroll
        for (int j = 0; j < 16; ++j) {
            unsigned long long kk = ((unsigned long long)fmono(sv[j]) << 32)
                                  | (unsigned long long)(0xFFFFFFFFu - (unsigned)gc[j]);
            if (kk > key) key = kk;
        }
        // reduce across the 16 tx lanes (lane bits 0..3)
#pragma unroll
        for (int d = 1; d < 16; d <<= 1) {
            unsigned int lo = (unsigned int)key;
            unsigned int hi = (unsigned int)(key >> 32);
            unsigned int olo = __shfl_xor(lo, d, 64);
            unsigned int ohi = __shfl_xor(hi, d, 64);
            unsigned long long o = ((unsigned long long)ohi << 32) | olo;
            if (o > key) key = o;
        }
        if (tx == 0) atomicMax(&rowMax[grow], key);
    }
}

// -------- per-row: init matches, claim column --------
__global__ __launch_bounds__(256) void rowwin_kernel(
    const unsigned long long* __restrict__ rowMax,
    unsigned long long* __restrict__ colWin,
    float* __restrict__ outMatches)
{
    int r = blockIdx.x * 256 + threadIdx.x;
    if (r >= NR) return;
    outMatches[r] = -1.0f;
    unsigned long long key = rowMax[r];
    unsigned int m = (unsigned int)(key >> 32);
    unsigned int bits = (m & 0x80000000u) ? (m ^ 0x80000000u) : ~m;
    float ms = __uint_as_float(bits);
    unsigned int col = 0xFFFFFFFFu - (unsigned int)key;
    if (ms > 0.3f) {
        unsigned long long ck = ((unsigned long long)m << 32)
                              | (unsigned long long)(0xFFFFFFFFu - (unsigned)r);
        atomicMax(&colWin[col], ck);
    }
}

// -------- per-column: winner takes the column --------
__global__ __launch_bounds__(256) void colfin_kernel(
    const unsigned long long* __restrict__ colWin,
    float* __restrict__ outMatches)
{
    int j = blockIdx.x * 256 + threadIdx.x;
    if (j >= NR) return;
    unsigned long long w = colWin[j];
    if (w != 0ull) {
        unsigned int r = 0xFFFFFFFFu - (unsigned int)w;
        outMatches[r] = (float)j;
    }
}

extern "C" void kernel_launch(void* const* d_in, const int* in_sizes, int n_in,
                              void* d_out, int out_size, void* d_ws, size_t ws_size,
                              hipStream_t stream) {
    const float* detA = (const float*)d_in[0];
    const float* detB = (const float*)d_in[1];
    const float* W1   = (const float*)d_in[2];
    const float* b1   = (const float*)d_in[3];
    const float* W2   = (const float*)d_in[4];
    const float* b2   = (const float*)d_in[5];
    const float* freq = (const float*)d_in[6];
    float* out = (float*)d_out;

    char* ws = (char*)d_ws;
    float* trigA = (float*)(ws);                         // 56*8192*4 = 1,835,008
    float* trigB = (float*)(ws + 1835008);               // 1,835,008
    float* normA = (float*)(ws + 3670016);               // 32,768
    float* normB = (float*)(ws + 3702784);               // 32,768
    unsigned long long* rowMax = (unsigned long long*)(ws + 3735552); // 65,536
    unsigned long long* colWin = (unsigned long long*)(ws + 3801088); // 65,536

    (void)hipMemsetAsync(rowMax, 0, NR * 8, stream);
    (void)hipMemsetAsync(colWin, 0, NR * 8, stream);

    encode_kernel<<<64, 256, 0, stream>>>(detA, detB, W1, b1, W2, b2, freq,
                                          trigA, trigB, normA, normB);
    sim_kernel<<<(NR / BM) * (NR / BN), 256, 0, stream>>>(
        trigA, trigB, normA, normB, out + NR, rowMax);
    rowwin_kernel<<<NR / 256, 256, 0, stream>>>(rowMax, colWin, out);
    colfin_kernel<<<NR / 256, 256, 0, stream>>>(colWin, out);
}

// Round 8
// 169.340 us; speedup vs baseline: 27.3297x; 1.0400x over previous
//
#include <hip/hip_runtime.h>
#include <math.h>

#define NR 8192
#define D_IN 4
#define H_DIM 64
#define N_OSC 28
#define KC 28          // k-chunk (28 cos rows, then 28 sin rows)
#define BM 128
#define BN 128
#define TWO_PI_F 6.28318530717958647692f   // rounds to f32 2*pi

typedef float f32x4 __attribute__((ext_vector_type(4)));

#define AS3(p) ((__attribute__((address_space(3))) void*)(p))
#define AS1C(p) ((const __attribute__((address_space(1))) void*)(p))

__device__ __forceinline__ float modpos(float x) {
    float r = fmodf(x, TWO_PI_F);
    if (r < 0.0f) r += TWO_PI_F;   // np.mod semantics (divisor > 0)
    return r;
}

__device__ __forceinline__ unsigned int fmono(float f) {
    unsigned int u = __float_as_uint(f);
    return (u & 0x80000000u) ? ~u : (u | 0x80000000u);
}

// -------- phase encode + advance + trig + norm --------
__global__ __launch_bounds__(256) void encode_kernel(
    const float* __restrict__ detA, const float* __restrict__ detB,
    const float* __restrict__ W1, const float* __restrict__ b1,
    const float* __restrict__ W2, const float* __restrict__ b2,
    const float* __restrict__ freq,
    float* __restrict__ trigA, float* __restrict__ trigB,
    float* __restrict__ normA, float* __restrict__ normB)
{
    __shared__ float sW1[D_IN * H_DIM];
    __shared__ float sb1[H_DIM];
    __shared__ float sW2[H_DIM * N_OSC];
    __shared__ float sb2[N_OSC];
    __shared__ float sDelta[N_OSC];

    int t = threadIdx.x;
    for (int i = t; i < D_IN * H_DIM; i += 256) sW1[i] = W1[i];
    for (int i = t; i < H_DIM; i += 256) sb1[i] = b1[i];
    for (int i = t; i < H_DIM * N_OSC; i += 256) sW2[i] = W2[i];
    for (int i = t; i < N_OSC; i += 256) {
        sb2[i] = b2[i];
        float d = TWO_PI_F * freq[i];   // (TWO_PI * frequencies) in f32
        sDelta[i] = d * 0.01f;          // ... * DT
    }
    __syncthreads();

    int gid = blockIdx.x * 256 + t;
    bool isA = gid < NR;
    int row = isA ? gid : gid - NR;
    const float* det = isA ? detA : detB;
    float* trig = isA ? trigA : trigB;
    float* nrm  = isA ? normA : normB;

    float4 xv = *(const float4*)(det + (size_t)row * 4);
    float x0 = xv.x, x1 = xv.y, x2 = xv.z, x3 = xv.w;

    float h[H_DIM];
#pragma unroll
    for (int j = 0; j < H_DIM; ++j) {
        float a = x0 * sW1[0 * H_DIM + j];
        a += x1 * sW1[1 * H_DIM + j];
        a += x2 * sW1[2 * H_DIM + j];
        a += x3 * sW1[3 * H_DIM + j];
        a += sb1[j];
        h[j] = fmaxf(a, 0.0f);
    }

    float raw[N_OSC];
#pragma unroll
    for (int o = 0; o < N_OSC; ++o) raw[o] = 0.0f;
#pragma unroll
    for (int j = 0; j < H_DIM; ++j) {
        float hj = h[j];
#pragma unroll
        for (int o = 0; o < N_OSC; ++o) raw[o] += hj * sW2[j * N_OSC + o];
    }

    float csum = 0.0f;
#pragma unroll
    for (int o = 0; o < N_OSC; ++o) {
        float p = raw[o] + sb2[o];
        p = modpos(p);
        if (isA) {
            float d = sDelta[o];
#pragma unroll
            for (int s = 0; s < 5; ++s) { p = modpos(p + d); }
        }
        float sn, cs;
        sincosf(p, &sn, &cs);
        csum += cs * cs + sn * sn;
        trig[(size_t)o * NR + row] = cs;
        trig[(size_t)(N_OSC + o) * NR + row] = sn;
    }
    nrm[row] = sqrtf(csum) + 1e-6f;
}

// -------- sim tile GEMM (K=56 as 2x28), 8x8 tile, glds staging, 4 waves/SIMD --------
__global__ __launch_bounds__(256) void sim_kernel(
    const float* __restrict__ trigA, const float* __restrict__ trigB,
    const float* __restrict__ normA, const float* __restrict__ normB,
    float* __restrict__ simOut, unsigned long long* __restrict__ rowMax)
{
    __shared__ __align__(16) float As[KC * BM];   // 14336 B
    __shared__ __align__(16) float Bs[KC * BN];   // 14336 B

    // bijective XCD swizzle: 4096 blocks, 8 XCDs, 512 contiguous tiles per XCD
    int bid = blockIdx.x;
    int swz = (bid & 7) * 512 + (bid >> 3);
    int bx = swz & 63;         // 64 col tiles (BN=128)
    int by = swz >> 6;         // 64 row tiles (BM=128)

    int r0 = by * BM;
    int c0 = bx * BN;
    int t = threadIdx.x;
    int tx = t & 15, ty = t >> 4;
    int tx4 = tx * 4, ty4 = ty * 4;
    int w = t >> 6, l = t & 63;

    float acc[8][8];
#pragma unroll
    for (int i = 0; i < 8; ++i)
#pragma unroll
        for (int j = 0; j < 8; ++j) acc[i][j] = 0.0f;

#pragma unroll
    for (int c = 0; c < 2; ++c) {
        // Zero-VGPR staging: each global_load_lds moves 64 lanes x 16B = 1024 B.
        // Unit u = 2 rows of 512 B; lane's row = 2u + (l>>5), col = (l&31)*4.
        for (int u = w; u < 14; u += 4) {
            const float* g = trigA + (size_t)(c * KC + 2 * u + (l >> 5)) * NR
                           + r0 + (l & 31) * 4;
            __builtin_amdgcn_global_load_lds(AS1C(g), AS3(&As[u * 256]), 16, 0, 0);
        }
        for (int v = w; v < 14; v += 4) {
            const float* g = trigB + (size_t)(c * KC + 2 * v + (l >> 5)) * NR
                           + c0 + (l & 31) * 4;
            __builtin_amdgcn_global_load_lds(AS1C(g), AS3(&Bs[v * 256]), 16, 0, 0);
        }
        __builtin_amdgcn_sched_barrier(0);
        __syncthreads();

#pragma unroll 4
        for (int k = 0; k < KC; ++k) {
            float a[8], b[8];
            *(float4*)&a[0] = *(const float4*)&As[k * BM + ty4];
            *(float4*)&a[4] = *(const float4*)&As[k * BM + 64 + ty4];
            *(float4*)&b[0] = *(const float4*)&Bs[k * BN + tx4];
            *(float4*)&b[4] = *(const float4*)&Bs[k * BN + 64 + tx4];
#pragma unroll
            for (int i = 0; i < 8; ++i)
#pragma unroll
                for (int j = 0; j < 8; ++j) acc[i][j] += a[i] * b[j];
        }
        __syncthreads();
    }

    float icn[8];
    int gc[8];
#pragma unroll
    for (int j = 0; j < 8; ++j) {
        int lc = (j < 4) ? (tx4 + j) : (64 + tx4 + (j - 4));
        gc[j] = c0 + lc;
        icn[j] = 1.0f / normB[c0 + lc];
    }

#pragma unroll
    for (int i = 0; i < 8; ++i) {
        int lr = (i < 4) ? (ty4 + i) : (64 + ty4 + (i - 4));
        int grow = r0 + lr;
        float irn = 1.0f / normA[grow];
        float sv[8];
#pragma unroll
        for (int j = 0; j < 8; ++j) sv[j] = acc[i][j] * (irn * icn[j]);

        size_t base = (size_t)grow * NR + c0;
        f32x4 w0, w1;
        w0.x = sv[0]; w0.y = sv[1]; w0.z = sv[2]; w0.w = sv[3];
        w1.x = sv[4]; w1.y = sv[5]; w1.z = sv[6]; w1.w = sv[7];
        __builtin_nontemporal_store(w0, (f32x4*)&simOut[base + tx4]);
        __builtin_nontemporal_store(w1, (f32x4*)&simOut[base + 64 + tx4]);

        // packed (monotone-sim | ~col) row max; smaller col wins ties
        unsigned long long key = 0ull;
#pragma unroll
        for (int j = 0; j < 8; ++j) {
            unsigned long long kk = ((unsigned long long)fmono(sv[j]) << 32)
                                  | (unsigned long long)(0xFFFFFFFFu - (unsigned)gc[j]);
            if (kk > key) key = kk;
        }
        // reduce across the 16 tx lanes (lane bits 0..3)
#pragma unroll
        for (int d = 1; d < 16; d <<= 1) {
            unsigned int lo = (unsigned int)key;
            unsigned int hi = (unsigned int)(key >> 32);
            unsigned int olo = __shfl_xor(lo, d, 64);
            unsigned int ohi = __shfl_xor(hi, d, 64);
            unsigned long long o = ((unsigned long long)ohi << 32) | olo;
            if (o > key) key = o;
        }
        if (tx == 0) atomicMax(&rowMax[grow], key);
    }
}

// -------- per-row: init matches, claim column --------
__global__ __launch_bounds__(256) void rowwin_kernel(
    const unsigned long long* __restrict__ rowMax,
    unsigned long long* __restrict__ colWin,
    float* __restrict__ outMatches)
{
    int r = blockIdx.x * 256 + threadIdx.x;
    if (r >= NR) return;
    outMatches[r] = -1.0f;
    unsigned long long key = rowMax[r];
    unsigned int m = (unsigned int)(key >> 32);
    unsigned int bits = (m & 0x80000000u) ? (m ^ 0x80000000u) : ~m;
    float ms = __uint_as_float(bits);
    unsigned int col = 0xFFFFFFFFu - (unsigned int)key;
    if (ms > 0.3f) {
        unsigned long long ck = ((unsigned long long)m << 32)
                              | (unsigned long long)(0xFFFFFFFFu - (unsigned)r);
        atomicMax(&colWin[col], ck);
    }
}

// -------- per-column: winner takes the column --------
__global__ __launch_bounds__(256) void colfin_kernel(
    const unsigned long long* __restrict__ colWin,
    float* __restrict__ outMatches)
{
    int j = blockIdx.x * 256 + threadIdx.x;
    if (j >= NR) return;
    unsigned long long w = colWin[j];
    if (w != 0ull) {
        unsigned int r = 0xFFFFFFFFu - (unsigned int)w;
        outMatches[r] = (float)j;
    }
}

extern "C" void kernel_launch(void* const* d_in, const int* in_sizes, int n_in,
                              void* d_out, int out_size, void* d_ws, size_t ws_size,
                              hipStream_t stream) {
    const float* detA = (const float*)d_in[0];
    const float* detB = (const float*)d_in[1];
    const float* W1   = (const float*)d_in[2];
    const float* b1   = (const float*)d_in[3];
    const float* W2   = (const float*)d_in[4];
    const float* b2   = (const float*)d_in[5];
    const float* freq = (const float*)d_in[6];
    float* out = (float*)d_out;

    char* ws = (char*)d_ws;
    float* trigA = (float*)(ws);                         // 56*8192*4 = 1,835,008
    float* trigB = (float*)(ws + 1835008);               // 1,835,008
    float* normA = (float*)(ws + 3670016);               // 32,768
    float* normB = (float*)(ws + 3702784);               // 32,768
    unsigned long long* rowMax = (unsigned long long*)(ws + 3735552); // 65,536
    unsigned long long* colWin = (unsigned long long*)(ws + 3801088); // 65,536

    (void)hipMemsetAsync(rowMax, 0, NR * 8, stream);
    (void)hipMemsetAsync(colWin, 0, NR * 8, stream);

    encode_kernel<<<64, 256, 0, stream>>>(detA, detB, W1, b1, W2, b2, freq,
                                          trigA, trigB, normA, normB);
    sim_kernel<<<(NR / BM) * (NR / BN), 256, 0, stream>>>(
        trigA, trigB, normA, normB, out + NR, rowMax);
    rowwin_kernel<<<NR / 256, 256, 0, stream>>>(rowMax, colWin, out);
    colfin_kernel<<<NR / 256, 256, 0, stream>>>(colWin, out);
}